// Round 1
// 254.239 us; speedup vs baseline: 1.0271x; 1.0271x over previous
//
#include <hip/hip_runtime.h>
#include <hip/hip_bf16.h>
#include <stdint.h>

// Problem constants (match reference setup_inputs)
static constexpr int Nn   = 50000;   // nodes
static constexpr int Ee   = 800000;  // edges per layer
static constexpr int Tt   = 8;       // time steps
static constexpr int CIN  = 16;
static constexpr int HID  = 16;
static constexpr int COUT = 32;
static constexpr int TC   = Tt * CIN;   // 128 channels per node
static constexpr int ROWD = TC / 2;     // 64 dwords per node row (bf16-pair packed)

// CSR build: g = layer*Nn + dst in [0, 2N); bucket = g>>8
static constexpr int NB  = (2 * Nn + 255) / 256;  // 391 buckets
static constexpr int CAP = 16;                    // staged records per bucket

// binning geometry: single pass, contiguous record range per block
static constexpr int BINB = 768;                          // bin blocks (3/CU @ 53KB LDS)
static constexpr int EPB  = (2 * Ee + BINB - 1) / BINB;   // 2084 records/block
static constexpr int TRB  = 1536;                         // transpose backfill blocks

typedef __attribute__((ext_vector_type(8))) short short8;
typedef __attribute__((ext_vector_type(4))) float f32x4;
union FU { uint4 u4; short8 s8; };

__device__ inline float bflo(uint32_t u) { return __uint_as_float(u << 16); }
__device__ inline float bfhi(uint32_t u) { return __uint_as_float(u & 0xffff0000u); }
__device__ inline unsigned short f2bf(float x) {
    __hip_bfloat16 h = __float2bfloat16(x);
    unsigned short u; __builtin_memcpy(&u, &h, 2); return u;
}
__device__ inline uint32_t bfpack(float a, float b) {
    return (uint32_t)f2bf(a) | ((uint32_t)f2bf(b) << 16);
}
__device__ inline void fma8(float2& a0, float2& a1, float2& a2, float2& a3,
                            float w, uint4 r) {
    a0.x += w * bflo(r.x); a0.y += w * bfhi(r.x);
    a1.x += w * bflo(r.y); a1.y += w * bfhi(r.y);
    a2.x += w * bflo(r.z); a2.y += w * bfhi(r.z);
    a3.x += w * bflo(r.w); a3.y += w * bfhi(r.w);
}
__device__ inline void redg(float2& a) {
    a.x += __shfl_xor(a.x, 16); a.y += __shfl_xor(a.y, 16);
    a.x += __shfl_xor(a.x, 32); a.y += __shfl_xor(a.y, 32);
}

// ---------------- count + dtype detect + weight packing ----------------
// Blocks 0..255: bucket histogram of dst over both layers.
// Block 256: dtype detect (fp32 junk-mantissa heuristic) + stage weights/bias.
// bucketCnt must be pre-zeroed (hipMemsetAsync).
__global__ __launch_bounds__(256) void k_count_detect(
        const int* __restrict__ ei0, const int* __restrict__ ei1,
        int* __restrict__ bucketCnt,
        const unsigned short* __restrict__ x16, int nvals,
        int* __restrict__ flag,
        const void* W1, const void* b1, const void* W2, const void* b2,
        float* __restrict__ biasbuf,
        uint32_t* __restrict__ wpk1, uint32_t* __restrict__ wpk2) {
    int tid = threadIdx.x;
    if (blockIdx.x >= 256) {
        // ---- detect + stage (one block) ----
        __shared__ int bad;
        if (tid == 0) bad = 0;
        __syncthreads();
        for (int i = tid; i < nvals; i += 256) {
            int ex = (x16[i] >> 7) & 0xFF;
            if (ex >= 0x8D) atomicOr(&bad, 1);
        }
        __syncthreads();
        int f = bad;
        if (tid == 0) flag[0] = f;
        auto ldf = [&](const void* srcp, int idx) -> float {
            return f ? ((const float*)srcp)[idx]
                     : __bfloat162float(((const __hip_bfloat16*)srcp)[idx]);
        };
        if (tid < 16) biasbuf[tid] = ldf(b1, tid);
        if (tid >= 16 && tid < 48) biasbuf[tid] = ldf(b2, tid - 16);
        { int h = tid >> 4, d = tid & 15;                       // 256 = 16h x 16d
          wpk1[tid] = bfpack(ldf(W1, 2 * d * 16 + h), ldf(W1, (2 * d + 1) * 16 + h)); }
        for (int i = tid; i < 512; i += 256) {                  // 512 = 32h x 16d
            int h = i >> 4, d = i & 15;
            wpk2[i] = bfpack(ldf(W2, 2 * d * 32 + h), ldf(W2, (2 * d + 1) * 32 + h));
        }
        return;
    }
    // ---- histogram ----
    __shared__ int hist[NB];
    for (int i = tid; i < NB; i += 256) hist[i] = 0;
    __syncthreads();
    const int4* d0 = (const int4*)(ei0 + Ee);
    const int4* d1 = (const int4*)(ei1 + Ee);
    int stride = 256 * 256;
    int nq = Ee / 4;
    for (int i = blockIdx.x * 256 + tid; i < 2 * nq; i += stride) {
        int4 v; int addn;
        if (i < nq) { v = d0[i]; addn = 0; }
        else        { v = d1[i - nq]; addn = Nn; }
        atomicAdd(&hist[(v.x + addn) >> 8], 1);
        atomicAdd(&hist[(v.y + addn) >> 8], 1);
        atomicAdd(&hist[(v.z + addn) >> 8], 1);
        atomicAdd(&hist[(v.w + addn) >> 8], 1);
    }
    __syncthreads();
    for (int i = tid; i < NB; i += 256)
        if (hist[i]) atomicAdd(&bucketCnt[i], hist[i]);
}

__global__ void k_bucketscan(const int* __restrict__ bucketCnt,
                             int* __restrict__ base, int* __restrict__ gcur) {
    __shared__ int tmp[512];
    int tid = threadIdx.x;
    int v = (tid < NB) ? bucketCnt[tid] : 0;
    tmp[tid] = v;
    __syncthreads();
    for (int ofs = 1; ofs < 512; ofs <<= 1) {
        int t = (tid >= ofs) ? tmp[tid - ofs] : 0;
        __syncthreads();
        tmp[tid] += t;
        __syncthreads();
    }
    if (tid < NB) { int b = tmp[tid] - v; base[tid] = b; gcur[tid] = b; }
    if (tid == 0) base[NB] = 2 * Ee;
}

// ---------------- fused binning + X-transpose ----------------
// Blocks [0,BINB): single-pass bucket scatter. Each block owns a contiguous
// record range (~2084 recs, Poisson(~5.3)/bucket so CAP=16 overflow ~never).
//   phase 1: LDS scatter, bank-swizzled rows[b][idx^(b&15)]
//   phase 2: one pipelined gcur atomic per non-empty bucket (block-wide)
//   phase 3: wave-coalesced write-out, 16-lane group per bucket (128B burst)
// rec64 = (g<<32) | (src<<16) | bf16(w).
// Blocks [BINB, BINB+TRB): X[T,N,CIN] -> xrows[N][64] bf16-pair transpose
// (grid-stride backfill; hides under bin's latency-bound phase).
__global__ __launch_bounds__(256) void k_bin_tr(const int* __restrict__ flag,
        const int* __restrict__ ei0, const void* w0v,
        const int* __restrict__ ei1, const void* w1v,
        int* __restrict__ gcur, uint64_t* __restrict__ gout,
        const void* Xv, uint32_t* __restrict__ xrows) {
    __shared__ uint64_t rows[NB][CAP];   // 50,048 B
    __shared__ int cnt[NB];              //  1,564 B
    __shared__ int posArr[NB];           //  1,564 B  -> 53.2 KB, 3 blocks/CU
    int tid = threadIdx.x;
    int bid = blockIdx.x;
    if (bid >= BINB) {
        // ---- transpose backfill ----
        int f = flag[0];
        int stride = TRB * 256;
        for (int i = (bid - BINB) * 256 + tid; i < Nn * ROWD; i += stride) {
            int n = i >> 6;
            int l = i & 63;
            int t = l >> 3;
            int c = (l & 7) * 2;
            int sidx = (t * Nn + n) * CIN + c;
            uint32_t v;
            if (f) {
                float2 ab = ((const float2*)Xv)[sidx >> 1];
                v = bfpack(ab.x, ab.y);
            } else {
                const unsigned short* u = (const unsigned short*)Xv;
                v = (uint32_t)u[sidx] | ((uint32_t)u[sidx + 1] << 16);
            }
            xrows[i] = v;
        }
        return;
    }
    for (int i = tid; i < NB; i += 256) cnt[i] = 0;
    __syncthreads();
    int f = flag[0];
    int lo = bid * EPB;
    int hi = min(2 * Ee, lo + EPB);
    for (int e = lo + tid; e < hi; e += 256) {
        int g; uint32_t src, wb;
        if (e < Ee) {
            g = ei0[Ee + e];
            src = (uint32_t)ei0[e];
            wb = f ? f2bf(((const float*)w0v)[e])
                   : ((const unsigned short*)w0v)[e];
        } else {
            int e1 = e - Ee;
            g = Nn + ei1[Ee + e1];
            src = (uint32_t)ei1[e1];
            wb = f ? f2bf(((const float*)w1v)[e1])
                   : ((const unsigned short*)w1v)[e1];
        }
        uint64_t r = ((uint64_t)(uint32_t)g << 32) | (src << 16) | wb;
        int b = g >> 8;
        int idx = atomicAdd(&cnt[b], 1);
        if (idx < CAP) rows[b][idx ^ (b & (CAP - 1))] = r;   // bank swizzle
        else { int pos = atomicAdd(&gcur[b], 1); gout[pos] = r; }  // ~never
    }
    __syncthreads();
    // claim global regions: 391 independent atomics, pipelined block-wide
    for (int b = tid; b < NB; b += 256) {
        int c = min(cnt[b], CAP);
        posArr[b] = c ? atomicAdd(&gcur[b], c) : 0;
    }
    __syncthreads();
    // wave-coalesced write-out: each 16-lane group writes one bucket
    int wv = tid >> 6, lane = tid & 63;
    int q = lane >> 4, k = lane & 15;
    for (int b = wv * 4 + q; b < NB; b += 16) {
        int c = min(cnt[b], CAP);
        if (k < c) gout[posArr[b] + k] = rows[b][k ^ (b & (CAP - 1))];
    }
}

// Per-bucket: histogram+scan -> off[]; scatter into LDS stage; coalesced out.
__global__ __launch_bounds__(256) void k_csr(const int* __restrict__ base,
        const uint64_t* __restrict__ gout,
        int* __restrict__ off, uint32_t* __restrict__ rec) {
    __shared__ int hist[256];
    __shared__ int tmp[256];
    __shared__ int cur[256];
    __shared__ uint32_t stage[8192];   // 32 KB
    int b = blockIdx.x, tid = threadIdx.x;
    int lo = base[b], hi = base[b + 1];
    hist[tid] = 0;
    __syncthreads();
    for (int i = lo + tid; i < hi; i += 256) {
        int gl = (int)(gout[i] >> 32) & 255;
        atomicAdd(&hist[gl], 1);
    }
    __syncthreads();
    int v = hist[tid];
    tmp[tid] = v;
    __syncthreads();
    for (int ofs = 1; ofs < 256; ofs <<= 1) {
        int t = (tid >= ofs) ? tmp[tid - ofs] : 0;
        __syncthreads();
        tmp[tid] += t;
        __syncthreads();
    }
    int excl = tmp[tid] - v;
    int gg = (b << 8) + tid;
    if (gg < 2 * Nn) off[gg] = lo + excl;
    if (b == NB - 1 && tid == 0) off[2 * Nn] = 2 * Ee;
    int count = hi - lo;
    if (count <= 8192) {
        cur[tid] = excl;
        __syncthreads();
        for (int i = lo + tid; i < hi; i += 256) {
            uint64_t r = gout[i];
            int gl = (int)(r >> 32) & 255;
            int pos = atomicAdd(&cur[gl], 1);
            stage[pos] = (uint32_t)r;
        }
        __syncthreads();
        for (int i = tid; i < count; i += 256) rec[lo + i] = stage[i];
    } else {
        cur[tid] = lo + excl;
        __syncthreads();
        for (int i = lo + tid; i < hi; i += 256) {
            uint64_t r = gout[i];
            int gl = (int)(r >> 32) & 255;
            int pos = atomicAdd(&cur[gl], 1);
            rec[pos] = (uint32_t)r;
        }
    }
}

// ---------------- layer kernels ----------------
// 256 threads = 4 waves, one wave per node. Gather: lanes in 4 groups of 16;
// each group covers one edge's 256B row via dwordx4 (4 edges per wave-issue,
// x2 unrolled). Epilogue: per-node linear via mfma_f32_16x16x32_bf16 on a
// shared A-panel [4 nodes x 8 t][xs(16)|ag(16) k] (packed bf16, stride 20 dw).

__global__ __launch_bounds__(256) void k_layer1(
    const uint32_t* __restrict__ xrows, const int* __restrict__ off,
    const uint32_t* __restrict__ rec, const int* __restrict__ resid,
    const uint32_t* __restrict__ wpk1, const float* __restrict__ biasbuf,
    uint32_t* __restrict__ h1rows) {
    __shared__ __align__(16) uint32_t shA[32 * 20];
    int tid = threadIdx.x, wv = tid >> 6, lane = tid & 63;
    int g = lane >> 4, p = lane & 15;
    // prefetch B-fragment + bias (global, L2-hot; latency hidden by gather)
    uint4 bfr = ((const uint4*)wpk1)[p * 4 + g];
    float bias = biasbuf[p];
    int n = blockIdx.x * 4 + wv;
    int o0 = __builtin_amdgcn_readfirstlane(off[n]);
    int o1 = __builtin_amdgcn_readfirstlane(off[n + 1]);
    int rn = __builtin_amdgcn_readfirstlane(resid[n]);
    const uint4* xb = (const uint4*)xrows;   // 16 uint4 per node row
    uint4 xs4 = xb[rn * 16 + p];
    float2 a0 = {0.f, 0.f}, a1 = a0, a2 = a0, a3 = a0;
    for (int j = o0; j < o1; j += 8) {
        int j0 = j + g, j1 = j + 4 + g;
        uint32_t e0 = rec[min(j0, o1 - 1)];
        uint32_t e1 = rec[min(j1, o1 - 1)];
        uint4 r0 = xb[(int)(e0 >> 16) * 16 + p];
        uint4 r1 = xb[(int)(e1 >> 16) * 16 + p];
        float w0 = (j0 < o1) ? bflo(e0) : 0.f;
        float w1 = (j1 < o1) ? bflo(e1) : 0.f;
        fma8(a0, a1, a2, a3, w0, r0);
        fma8(a0, a1, a2, a3, w1, r1);
    }
    redg(a0); redg(a1); redg(a2); redg(a3);
    float inv = 1.f / (float)max(o1 - o0, 1);
    uint4 agp;
    agp.x = bfpack(a0.x * inv, a0.y * inv);
    agp.y = bfpack(a1.x * inv, a1.y * inv);
    agp.z = bfpack(a2.x * inv, a2.y * inv);
    agp.w = bfpack(a3.x * inv, a3.y * inv);
    // A-panel write: row r = wv*8 + t; [xs dwords 0..7 | ag dwords 8..15]
    int r = wv * 8 + (p >> 1);
    int hs = (p & 1) * 4;
    if (g == 0)      *(uint4*)&shA[r * 20 + hs] = xs4;
    else if (g == 1) *(uint4*)&shA[r * 20 + 8 + hs] = agp;
    __syncthreads();
    // MFMA: wave-pair (wv>>1) covers 2 nodes = 16 rows; A[m= p][k=8g+j]
    FU fa, fb; fb.u4 = bfr;
    fa.u4 = *(const uint4*)&shA[((wv >> 1) * 16 + p) * 20 + 4 * g];
    f32x4 acc = {bias, bias, bias, bias};
    acc = __builtin_amdgcn_mfma_f32_16x16x32_bf16(fa.s8, fb.s8, acc, 0, 0, 0);
    // C: col=p (h), row=g*4+reg; node_local=row>>3; this wave stores own node
    bool mine = ((g >> 1) == (wv & 1));
#pragma unroll
    for (int rg = 0; rg < 4; rg++) {
        float v = acc[rg];
        v = fmaxf(v, 0.01f * v);          // leaky_relu(0.01)
        float vn = __shfl_xor(v, 1);      // neighbor h for bf16 pair pack
        if (mine && !(p & 1)) {
            int t = (g & 1) * 4 + rg;
            h1rows[n * 64 + t * 8 + (p >> 1)] = bfpack(v, vn);
        }
    }
}

__global__ __launch_bounds__(256) void k_layer2(
    const int* __restrict__ flag,
    const uint32_t* __restrict__ h1rows, const int* __restrict__ off,
    const uint32_t* __restrict__ rec, const int* __restrict__ resid,
    const uint32_t* __restrict__ wpk2, const float* __restrict__ biasbuf,
    void* __restrict__ outv) {
    __shared__ __align__(16) uint32_t shA[32 * 20];
    int tid = threadIdx.x, wv = tid >> 6, lane = tid & 63;
    int g = lane >> 4, p = lane & 15;
    uint4 b0 = ((const uint4*)wpk2)[p * 4 + g];          // h = p
    uint4 b1v = ((const uint4*)wpk2)[(p + 16) * 4 + g];  // h = p+16
    float bias0 = biasbuf[16 + p];
    float bias1 = biasbuf[32 + p];
    int f = flag[0];
    int n = blockIdx.x * 4 + wv;
    int o0 = __builtin_amdgcn_readfirstlane(off[Nn + n]);
    int o1 = __builtin_amdgcn_readfirstlane(off[Nn + n + 1]);
    int rn = __builtin_amdgcn_readfirstlane(resid[n]);
    const uint4* xb = (const uint4*)h1rows;
    uint4 xs4 = xb[rn * 16 + p];
    float2 a0 = {0.f, 0.f}, a1 = a0, a2 = a0, a3 = a0;
    for (int j = o0; j < o1; j += 8) {
        int j0 = j + g, j1 = j + 4 + g;
        uint32_t e0 = rec[min(j0, o1 - 1)];
        uint32_t e1 = rec[min(j1, o1 - 1)];
        uint4 r0 = xb[(int)(e0 >> 16) * 16 + p];
        uint4 r1 = xb[(int)(e1 >> 16) * 16 + p];
        float w0 = (j0 < o1) ? bflo(e0) : 0.f;
        float w1 = (j1 < o1) ? bflo(e1) : 0.f;
        fma8(a0, a1, a2, a3, w0, r0);
        fma8(a0, a1, a2, a3, w1, r1);
    }
    redg(a0); redg(a1); redg(a2); redg(a3);
    float inv = 1.f / (float)max(o1 - o0, 1);
    uint4 agp;
    agp.x = bfpack(a0.x * inv, a0.y * inv);
    agp.y = bfpack(a1.x * inv, a1.y * inv);
    agp.z = bfpack(a2.x * inv, a2.y * inv);
    agp.w = bfpack(a3.x * inv, a3.y * inv);
    int r = wv * 8 + (p >> 1);
    int hs = (p & 1) * 4;
    if (g == 0)      *(uint4*)&shA[r * 20 + hs] = xs4;
    else if (g == 1) *(uint4*)&shA[r * 20 + 8 + hs] = agp;
    __syncthreads();
    FU fa, fb0, fb1; fb0.u4 = b0; fb1.u4 = b1v;
    fa.u4 = *(const uint4*)&shA[((wv >> 1) * 16 + p) * 20 + 4 * g];
    f32x4 acc0 = {bias0, bias0, bias0, bias0};
    f32x4 acc1 = {bias1, bias1, bias1, bias1};
    acc0 = __builtin_amdgcn_mfma_f32_16x16x32_bf16(fa.s8, fb0.s8, acc0, 0, 0, 0);
    acc1 = __builtin_amdgcn_mfma_f32_16x16x32_bf16(fa.s8, fb1.s8, acc1, 0, 0, 0);
    bool mine = ((g >> 1) == (wv & 1));
    if (mine) {
#pragma unroll
        for (int rg = 0; rg < 4; rg++) {
            int t = (g & 1) * 4 + rg;
            size_t idx = ((size_t)(t * Nn + n)) * COUT + p;
            float v = acc0[rg]; v = fmaxf(v, 0.01f * v);
            float u = acc1[rg]; u = fmaxf(u, 0.01f * u);
            if (f) {
                ((float*)outv)[idx] = v;
                ((float*)outv)[idx + 16] = u;
            } else {
                ((__hip_bfloat16*)outv)[idx] = __float2bfloat16(v);
                ((__hip_bfloat16*)outv)[idx + 16] = __float2bfloat16(u);
            }
        }
    }
}

// ---------------- launch ----------------

extern "C" void kernel_launch(void* const* d_in, const int* in_sizes, int n_in,
                              void* d_out, int out_size, void* d_ws, size_t ws_size,
                              hipStream_t stream) {
    const void* X   = d_in[0];
    const int* ei0  = (const int*)d_in[1];
    const void* w0  = d_in[2];
    const int* ei1  = (const int*)d_in[3];
    const void* w1  = d_in[4];
    const int* rn0  = (const int*)d_in[5];
    const int* rn1  = (const int*)d_in[6];
    const void* W1  = d_in[7];
    const void* b1  = d_in[8];
    const void* W2  = d_in[9];
    const void* b2  = d_in[10];

    // workspace carve-up (256B aligned) — total ~32.5 MB
    char* ws = (char*)d_ws;
    size_t p = 0;
    auto alloc = [&](size_t bytes) -> char* {
        p = (p + 255) & ~(size_t)255;
        char* r = ws + p;
        p += bytes;
        return r;
    };
    int* flag        = (int*)alloc(4);
    float* biasbuf   = (float*)alloc(48 * 4);
    uint32_t* wpk1   = (uint32_t*)alloc(256 * 4);
    uint32_t* wpk2   = (uint32_t*)alloc(512 * 4);
    int* bucketCnt   = (int*)alloc(NB * 4);
    int* base        = (int*)alloc((NB + 1) * 4);
    int* gcur        = (int*)alloc(NB * 4);
    int* off         = (int*)alloc(((size_t)2 * Nn + 1) * 4);    // 400 KB
    uint32_t* recf   = (uint32_t*)alloc((size_t)2 * Ee * 4);     // 6.4 MB
    uint32_t* h1rows = (uint32_t*)alloc((size_t)Nn * ROWD * 4);  // 12.8 MB
    uint64_t* gout   = (uint64_t*)alloc((size_t)2 * Ee * 8);     // 12.8 MB
    // xrows lives in d_out (51.2 MB out buffer, fully overwritten by k_layer2;
    // can no longer alias gout since transpose overlaps binning)
    uint32_t* xrows  = (uint32_t*)d_out;

    hipMemsetAsync(bucketCnt, 0, NB * sizeof(int), stream);
    hipLaunchKernelGGL(k_count_detect, dim3(257), dim3(256), 0, stream,
                       ei0, ei1, bucketCnt,
                       (const unsigned short*)X, 16384, flag, W1, b1, W2, b2,
                       biasbuf, wpk1, wpk2);
    hipLaunchKernelGGL(k_bucketscan, dim3(1), dim3(512), 0, stream,
                       bucketCnt, base, gcur);
    hipLaunchKernelGGL(k_bin_tr, dim3(BINB + TRB), dim3(256), 0, stream,
                       flag, ei0, w0, ei1, w1, gcur, gout, X, xrows);
    hipLaunchKernelGGL(k_csr, dim3(NB), dim3(256), 0, stream,
                       base, gout, off, recf);
    hipLaunchKernelGGL(k_layer1, dim3(Nn / 4), dim3(256), 0, stream,
                       xrows, off, recf, rn0, wpk1, biasbuf, h1rows);
    hipLaunchKernelGGL(k_layer2, dim3(Nn / 4), dim3(256), 0, stream,
                       flag, h1rows, off, recf, rn1, wpk2, biasbuf, d_out);
    (void)in_sizes; (void)n_in; (void)out_size; (void)ws_size;
}

// Round 5
// 245.415 us; speedup vs baseline: 1.0641x; 1.0360x over previous
//
#include <hip/hip_runtime.h>
#include <hip/hip_bf16.h>
#include <stdint.h>

// Problem constants (match reference setup_inputs)
static constexpr int Nn   = 50000;   // nodes
static constexpr int Ee   = 800000;  // edges per layer
static constexpr int Tt   = 8;       // time steps
static constexpr int CIN  = 16;
static constexpr int HID  = 16;
static constexpr int COUT = 32;
static constexpr int TC   = Tt * CIN;   // 128 channels per node
static constexpr int ROWD = TC / 2;     // 64 dwords per node row (bf16-pair packed)

// CSR build: g = layer*Nn + dst in [0, 2N); bucket = g>>8
static constexpr int NB  = (2 * Nn + 255) / 256;  // 391 buckets
static constexpr int CAP = 16;                    // staged records per bucket
static constexpr int GSTR = 32;                   // gcur line stride (128B anti-contention)

// binning geometry
static constexpr int BINB = 768;                          // bin blocks (3/CU @ 53KB LDS)
static constexpr int EPB  = (2 * Ee + BINB - 1) / BINB;   // records/block
static constexpr int TRB  = 1536;                         // transpose backfill blocks

typedef __attribute__((ext_vector_type(8))) short short8;
typedef __attribute__((ext_vector_type(4))) float f32x4;
union FU { uint4 u4; short8 s8; };

__device__ inline float bflo(uint32_t u) { return __uint_as_float(u << 16); }
__device__ inline float bfhi(uint32_t u) { return __uint_as_float(u & 0xffff0000u); }
__device__ inline unsigned short f2bf(float x) {
    __hip_bfloat16 h = __float2bfloat16(x);
    unsigned short u; __builtin_memcpy(&u, &h, 2); return u;
}
__device__ inline uint32_t bfpack(float a, float b) {
    return (uint32_t)f2bf(a) | ((uint32_t)f2bf(b) << 16);
}
__device__ inline void fma8(float2& a0, float2& a1, float2& a2, float2& a3,
                            float w, uint4 r) {
    a0.x += w * bflo(r.x); a0.y += w * bfhi(r.x);
    a1.x += w * bflo(r.y); a1.y += w * bfhi(r.y);
    a2.x += w * bflo(r.z); a2.y += w * bfhi(r.z);
    a3.x += w * bflo(r.w); a3.y += w * bfhi(r.w);
}
__device__ inline void redg(float2& a) {
    a.x += __shfl_xor(a.x, 16); a.y += __shfl_xor(a.y, 16);
    a.x += __shfl_xor(a.x, 32); a.y += __shfl_xor(a.y, 32);
}

// ---------------- count + dtype detect + weight packing ----------------
// Blocks 0..255: bucket histogram of dst over both layers.
// Block 256: dtype detect (fp32 junk-mantissa heuristic) + stage weights/bias.
// bucketCnt must be pre-zeroed (hipMemsetAsync).
__global__ __launch_bounds__(256) void k_count_detect(
        const int* __restrict__ ei0, const int* __restrict__ ei1,
        int* __restrict__ bucketCnt,
        const unsigned short* __restrict__ x16, int nvals,
        int* __restrict__ flag,
        const void* W1, const void* b1, const void* W2, const void* b2,
        float* __restrict__ biasbuf,
        uint32_t* __restrict__ wpk1, uint32_t* __restrict__ wpk2) {
    int tid = threadIdx.x;
    if (blockIdx.x >= 256) {
        // ---- detect + stage (one block) ----
        __shared__ int bad;
        if (tid == 0) bad = 0;
        __syncthreads();
        for (int i = tid; i < nvals; i += 256) {
            int ex = (x16[i] >> 7) & 0xFF;
            if (ex >= 0x8D) atomicOr(&bad, 1);
        }
        __syncthreads();
        int f = bad;
        if (tid == 0) flag[0] = f;
        auto ldf = [&](const void* srcp, int idx) -> float {
            return f ? ((const float*)srcp)[idx]
                     : __bfloat162float(((const __hip_bfloat16*)srcp)[idx]);
        };
        if (tid < 16) biasbuf[tid] = ldf(b1, tid);
        if (tid >= 16 && tid < 48) biasbuf[tid] = ldf(b2, tid - 16);
        { int h = tid >> 4, d = tid & 15;                       // 256 = 16h x 16d
          wpk1[tid] = bfpack(ldf(W1, 2 * d * 16 + h), ldf(W1, (2 * d + 1) * 16 + h)); }
        for (int i = tid; i < 512; i += 256) {                  // 512 = 32h x 16d
            int h = i >> 4, d = i & 15;
            wpk2[i] = bfpack(ldf(W2, 2 * d * 32 + h), ldf(W2, (2 * d + 1) * 32 + h));
        }
        return;
    }
    // ---- histogram ----
    __shared__ int hist[NB];
    for (int i = tid; i < NB; i += 256) hist[i] = 0;
    __syncthreads();
    const int4* d0 = (const int4*)(ei0 + Ee);
    const int4* d1 = (const int4*)(ei1 + Ee);
    int stride = 256 * 256;
    int nq = Ee / 4;
    for (int i = blockIdx.x * 256 + tid; i < 2 * nq; i += stride) {
        int4 v; int addn;
        if (i < nq) { v = d0[i]; addn = 0; }
        else        { v = d1[i - nq]; addn = Nn; }
        atomicAdd(&hist[(v.x + addn) >> 8], 1);
        atomicAdd(&hist[(v.y + addn) >> 8], 1);
        atomicAdd(&hist[(v.z + addn) >> 8], 1);
        atomicAdd(&hist[(v.w + addn) >> 8], 1);
    }
    __syncthreads();
    for (int i = tid; i < NB; i += 256)
        if (hist[i]) atomicAdd(&bucketCnt[i], hist[i]);
}

__global__ void k_bucketscan(const int* __restrict__ bucketCnt,
                             int* __restrict__ base, int* __restrict__ gcur) {
    __shared__ int tmp[512];
    int tid = threadIdx.x;
    int v = (tid < NB) ? bucketCnt[tid] : 0;
    tmp[tid] = v;
    __syncthreads();
    for (int ofs = 1; ofs < 512; ofs <<= 1) {
        int t = (tid >= ofs) ? tmp[tid - ofs] : 0;
        __syncthreads();
        tmp[tid] += t;
        __syncthreads();
    }
    if (tid < NB) {
        int b = tmp[tid] - v;
        base[tid] = b;
        gcur[tid * GSTR] = b;   // one counter per 128B line (anti-contention)
    }
    if (tid == 0) base[NB] = 2 * Ee;
}

// ---------------- fused binning + X-transpose ----------------
// Blocks [0,BINB): single-pass bucket scatter.
//   phase 1: LDS scatter, bank-swizzled rows[b][idx^(b&15)]
//   phase 2: one pipelined gcur atomic per non-empty bucket (block-wide);
//            gcur is line-padded so per-line RMW serialization is 768, not 12K
//   phase 3: wave-coalesced write-out, 16-lane group per bucket (128B burst)
// rec64 = (g<<32) | (src<<16) | bf16(w).
// Blocks [BINB, BINB+TRB): X[T,N,CIN] -> xrows[N][64] bf16-pair transpose.
__global__ __launch_bounds__(256) void k_bin_tr(const int* __restrict__ flag,
        const int* __restrict__ ei0, const void* w0v,
        const int* __restrict__ ei1, const void* w1v,
        int* __restrict__ gcur, uint64_t* __restrict__ gout,
        const void* Xv, uint32_t* __restrict__ xrows) {
    __shared__ uint64_t rows[NB][CAP];   // 50,048 B
    __shared__ int cnt[NB];              //  1,564 B
    __shared__ int posArr[NB];           //  1,564 B  -> 53.2 KB, 3 blocks/CU
    int tid = threadIdx.x;
    int bid = blockIdx.x;
    if (bid >= BINB) {
        // ---- transpose backfill ----
        int f = flag[0];
        int stride = TRB * 256;
        for (int i = (bid - BINB) * 256 + tid; i < Nn * ROWD; i += stride) {
            int n = i >> 6;
            int l = i & 63;
            int t = l >> 3;
            int c = (l & 7) * 2;
            int sidx = (t * Nn + n) * CIN + c;
            uint32_t v;
            if (f) {
                float2 ab = ((const float2*)Xv)[sidx >> 1];
                v = bfpack(ab.x, ab.y);
            } else {
                const unsigned short* u = (const unsigned short*)Xv;
                v = (uint32_t)u[sidx] | ((uint32_t)u[sidx + 1] << 16);
            }
            xrows[i] = v;
        }
        return;
    }
    for (int i = tid; i < NB; i += 256) cnt[i] = 0;
    __syncthreads();
    int f = flag[0];
    int lo = bid * EPB;
    int hi = min(2 * Ee, lo + EPB);
    for (int e = lo + tid; e < hi; e += 256) {
        int g; uint32_t src, wb;
        if (e < Ee) {
            g = ei0[Ee + e];
            src = (uint32_t)ei0[e];
            wb = f ? f2bf(((const float*)w0v)[e])
                   : ((const unsigned short*)w0v)[e];
        } else {
            int e1 = e - Ee;
            g = Nn + ei1[Ee + e1];
            src = (uint32_t)ei1[e1];
            wb = f ? f2bf(((const float*)w1v)[e1])
                   : ((const unsigned short*)w1v)[e1];
        }
        uint64_t r = ((uint64_t)(uint32_t)g << 32) | (src << 16) | wb;
        int b = g >> 8;
        int idx = atomicAdd(&cnt[b], 1);
        if (idx < CAP) rows[b][idx ^ (b & (CAP - 1))] = r;   // bank swizzle
        else { int pos = atomicAdd(&gcur[b * GSTR], 1); gout[pos] = r; }  // ~never
    }
    __syncthreads();
    // claim global regions: 391 independent atomics, pipelined block-wide
    for (int b = tid; b < NB; b += 256) {
        int c = min(cnt[b], CAP);
        posArr[b] = c ? atomicAdd(&gcur[b * GSTR], c) : 0;
    }
    __syncthreads();
    // wave-coalesced write-out: each 16-lane group writes one bucket
    int wv = tid >> 6, lane = tid & 63;
    int q = lane >> 4, k = lane & 15;
    for (int b = wv * 4 + q; b < NB; b += 16) {
        int c = min(cnt[b], CAP);
        if (k < c) gout[posArr[b] + k] = rows[b][k ^ (b & (CAP - 1))];
    }
}

// Per-bucket: histogram+scan -> off[]; scatter into LDS stage; coalesced out.
__global__ __launch_bounds__(256) void k_csr(const int* __restrict__ base,
        const uint64_t* __restrict__ gout,
        int* __restrict__ off, uint32_t* __restrict__ rec) {
    __shared__ int hist[256];
    __shared__ int tmp[256];
    __shared__ int cur[256];
    __shared__ uint32_t stage[8192];   // 32 KB
    int b = blockIdx.x, tid = threadIdx.x;
    int lo = base[b], hi = base[b + 1];
    hist[tid] = 0;
    __syncthreads();
    for (int i = lo + tid; i < hi; i += 256) {
        int gl = (int)(gout[i] >> 32) & 255;
        atomicAdd(&hist[gl], 1);
    }
    __syncthreads();
    int v = hist[tid];
    tmp[tid] = v;
    __syncthreads();
    for (int ofs = 1; ofs < 256; ofs <<= 1) {
        int t = (tid >= ofs) ? tmp[tid - ofs] : 0;
        __syncthreads();
        tmp[tid] += t;
        __syncthreads();
    }
    int excl = tmp[tid] - v;
    int gg = (b << 8) + tid;
    if (gg < 2 * Nn) off[gg] = lo + excl;
    if (b == NB - 1 && tid == 0) off[2 * Nn] = 2 * Ee;
    int count = hi - lo;
    if (count <= 8192) {
        cur[tid] = excl;
        __syncthreads();
        for (int i = lo + tid; i < hi; i += 256) {
            uint64_t r = gout[i];
            int gl = (int)(r >> 32) & 255;
            int pos = atomicAdd(&cur[gl], 1);
            stage[pos] = (uint32_t)r;
        }
        __syncthreads();
        for (int i = tid; i < count; i += 256) rec[lo + i] = stage[i];
    } else {
        cur[tid] = lo + excl;
        __syncthreads();
        for (int i = lo + tid; i < hi; i += 256) {
            uint64_t r = gout[i];
            int gl = (int)(r >> 32) & 255;
            int pos = atomicAdd(&cur[gl], 1);
            rec[pos] = (uint32_t)r;
        }
    }
}

// ---------------- layer kernels ----------------
// 256 threads = 4 waves, one wave per node. Gather: lanes in 4 groups of 16;
// each group covers one edge's 256B row via dwordx4; 16 edges in flight per
// iteration (4 per group) to cover the mean degree (16) in one round.
// Epilogue: per-node linear via mfma_f32_16x16x32_bf16 on a shared A-panel.

__global__ __launch_bounds__(256) void k_layer1(
    const uint32_t* __restrict__ xrows, const int* __restrict__ off,
    const uint32_t* __restrict__ rec, const int* __restrict__ resid,
    const uint32_t* __restrict__ wpk1, const float* __restrict__ biasbuf,
    uint32_t* __restrict__ h1rows) {
    __shared__ __align__(16) uint32_t shA[32 * 20];
    int tid = threadIdx.x, wv = tid >> 6, lane = tid & 63;
    int g = lane >> 4, p = lane & 15;
    // prefetch B-fragment + bias (global, L2-hot; latency hidden by gather)
    uint4 bfr = ((const uint4*)wpk1)[p * 4 + g];
    float bias = biasbuf[p];
    int n = blockIdx.x * 4 + wv;
    int o0 = __builtin_amdgcn_readfirstlane(off[n]);
    int o1 = __builtin_amdgcn_readfirstlane(off[n + 1]);
    int rn = __builtin_amdgcn_readfirstlane(resid[n]);
    const uint4* xb = (const uint4*)xrows;   // 16 uint4 per node row
    uint4 xs4 = xb[rn * 16 + p];
    float2 a0 = {0.f, 0.f}, a1 = a0, a2 = a0, a3 = a0;
    for (int j = o0; j < o1; j += 16) {
        int j0 = j + g, j1 = j + 4 + g, j2 = j + 8 + g, j3 = j + 12 + g;
        uint32_t e0 = rec[min(j0, o1 - 1)];
        uint32_t e1 = rec[min(j1, o1 - 1)];
        uint32_t e2 = rec[min(j2, o1 - 1)];
        uint32_t e3 = rec[min(j3, o1 - 1)];
        uint4 r0 = xb[(int)(e0 >> 16) * 16 + p];
        uint4 r1 = xb[(int)(e1 >> 16) * 16 + p];
        uint4 r2 = xb[(int)(e2 >> 16) * 16 + p];
        uint4 r3 = xb[(int)(e3 >> 16) * 16 + p];
        float w0 = (j0 < o1) ? bflo(e0) : 0.f;
        float w1 = (j1 < o1) ? bflo(e1) : 0.f;
        float w2 = (j2 < o1) ? bflo(e2) : 0.f;
        float w3 = (j3 < o1) ? bflo(e3) : 0.f;
        fma8(a0, a1, a2, a3, w0, r0);
        fma8(a0, a1, a2, a3, w1, r1);
        fma8(a0, a1, a2, a3, w2, r2);
        fma8(a0, a1, a2, a3, w3, r3);
    }
    redg(a0); redg(a1); redg(a2); redg(a3);
    float inv = 1.f / (float)max(o1 - o0, 1);
    uint4 agp;
    agp.x = bfpack(a0.x * inv, a0.y * inv);
    agp.y = bfpack(a1.x * inv, a1.y * inv);
    agp.z = bfpack(a2.x * inv, a2.y * inv);
    agp.w = bfpack(a3.x * inv, a3.y * inv);
    // A-panel write: row r = wv*8 + t; [xs dwords 0..7 | ag dwords 8..15]
    int r = wv * 8 + (p >> 1);
    int hs = (p & 1) * 4;
    if (g == 0)      *(uint4*)&shA[r * 20 + hs] = xs4;
    else if (g == 1) *(uint4*)&shA[r * 20 + 8 + hs] = agp;
    __syncthreads();
    // MFMA: wave-pair (wv>>1) covers 2 nodes = 16 rows; A[m= p][k=8g+j]
    FU fa, fb; fb.u4 = bfr;
    fa.u4 = *(const uint4*)&shA[((wv >> 1) * 16 + p) * 20 + 4 * g];
    f32x4 acc = {bias, bias, bias, bias};
    acc = __builtin_amdgcn_mfma_f32_16x16x32_bf16(fa.s8, fb.s8, acc, 0, 0, 0);
    // C: col=p (h), row=g*4+reg; node_local=row>>3; this wave stores own node
    bool mine = ((g >> 1) == (wv & 1));
#pragma unroll
    for (int rg = 0; rg < 4; rg++) {
        float v = acc[rg];
        v = fmaxf(v, 0.01f * v);          // leaky_relu(0.01)
        float vn = __shfl_xor(v, 1);      // neighbor h for bf16 pair pack
        if (mine && !(p & 1)) {
            int t = (g & 1) * 4 + rg;
            h1rows[n * 64 + t * 8 + (p >> 1)] = bfpack(v, vn);
        }
    }
}

__global__ __launch_bounds__(256) void k_layer2(
    const int* __restrict__ flag,
    const uint32_t* __restrict__ h1rows, const int* __restrict__ off,
    const uint32_t* __restrict__ rec, const int* __restrict__ resid,
    const uint32_t* __restrict__ wpk2, const float* __restrict__ biasbuf,
    void* __restrict__ outv) {
    __shared__ __align__(16) uint32_t shA[32 * 20];
    int tid = threadIdx.x, wv = tid >> 6, lane = tid & 63;
    int g = lane >> 4, p = lane & 15;
    uint4 b0 = ((const uint4*)wpk2)[p * 4 + g];          // h = p
    uint4 b1v = ((const uint4*)wpk2)[(p + 16) * 4 + g];  // h = p+16
    float bias0 = biasbuf[16 + p];
    float bias1 = biasbuf[32 + p];
    int f = flag[0];
    int n = blockIdx.x * 4 + wv;
    int o0 = __builtin_amdgcn_readfirstlane(off[Nn + n]);
    int o1 = __builtin_amdgcn_readfirstlane(off[Nn + n + 1]);
    int rn = __builtin_amdgcn_readfirstlane(resid[n]);
    const uint4* xb = (const uint4*)h1rows;
    uint4 xs4 = xb[rn * 16 + p];
    float2 a0 = {0.f, 0.f}, a1 = a0, a2 = a0, a3 = a0;
    for (int j = o0; j < o1; j += 16) {
        int j0 = j + g, j1 = j + 4 + g, j2 = j + 8 + g, j3 = j + 12 + g;
        uint32_t e0 = rec[min(j0, o1 - 1)];
        uint32_t e1 = rec[min(j1, o1 - 1)];
        uint32_t e2 = rec[min(j2, o1 - 1)];
        uint32_t e3 = rec[min(j3, o1 - 1)];
        uint4 r0 = xb[(int)(e0 >> 16) * 16 + p];
        uint4 r1 = xb[(int)(e1 >> 16) * 16 + p];
        uint4 r2 = xb[(int)(e2 >> 16) * 16 + p];
        uint4 r3 = xb[(int)(e3 >> 16) * 16 + p];
        float w0 = (j0 < o1) ? bflo(e0) : 0.f;
        float w1 = (j1 < o1) ? bflo(e1) : 0.f;
        float w2 = (j2 < o1) ? bflo(e2) : 0.f;
        float w3 = (j3 < o1) ? bflo(e3) : 0.f;
        fma8(a0, a1, a2, a3, w0, r0);
        fma8(a0, a1, a2, a3, w1, r1);
        fma8(a0, a1, a2, a3, w2, r2);
        fma8(a0, a1, a2, a3, w3, r3);
    }
    redg(a0); redg(a1); redg(a2); redg(a3);
    float inv = 1.f / (float)max(o1 - o0, 1);
    uint4 agp;
    agp.x = bfpack(a0.x * inv, a0.y * inv);
    agp.y = bfpack(a1.x * inv, a1.y * inv);
    agp.z = bfpack(a2.x * inv, a2.y * inv);
    agp.w = bfpack(a3.x * inv, a3.y * inv);
    int r = wv * 8 + (p >> 1);
    int hs = (p & 1) * 4;
    if (g == 0)      *(uint4*)&shA[r * 20 + hs] = xs4;
    else if (g == 1) *(uint4*)&shA[r * 20 + 8 + hs] = agp;
    __syncthreads();
    FU fa, fb0, fb1; fb0.u4 = b0; fb1.u4 = b1v;
    fa.u4 = *(const uint4*)&shA[((wv >> 1) * 16 + p) * 20 + 4 * g];
    f32x4 acc0 = {bias0, bias0, bias0, bias0};
    f32x4 acc1 = {bias1, bias1, bias1, bias1};
    acc0 = __builtin_amdgcn_mfma_f32_16x16x32_bf16(fa.s8, fb0.s8, acc0, 0, 0, 0);
    acc1 = __builtin_amdgcn_mfma_f32_16x16x32_bf16(fa.s8, fb1.s8, acc1, 0, 0, 0);
    bool mine = ((g >> 1) == (wv & 1));
    if (mine) {
#pragma unroll
        for (int rg = 0; rg < 4; rg++) {
            int t = (g & 1) * 4 + rg;
            size_t idx = ((size_t)(t * Nn + n)) * COUT + p;
            float v = acc0[rg]; v = fmaxf(v, 0.01f * v);
            float u = acc1[rg]; u = fmaxf(u, 0.01f * u);
            if (f) {
                ((float*)outv)[idx] = v;
                ((float*)outv)[idx + 16] = u;
            } else {
                ((__hip_bfloat16*)outv)[idx] = __float2bfloat16(v);
                ((__hip_bfloat16*)outv)[idx + 16] = __float2bfloat16(u);
            }
        }
    }
}

// ---------------- launch ----------------

extern "C" void kernel_launch(void* const* d_in, const int* in_sizes, int n_in,
                              void* d_out, int out_size, void* d_ws, size_t ws_size,
                              hipStream_t stream) {
    const void* X   = d_in[0];
    const int* ei0  = (const int*)d_in[1];
    const void* w0  = d_in[2];
    const int* ei1  = (const int*)d_in[3];
    const void* w1  = d_in[4];
    const int* rn0  = (const int*)d_in[5];
    const int* rn1  = (const int*)d_in[6];
    const void* W1  = d_in[7];
    const void* b1  = d_in[8];
    const void* W2  = d_in[9];
    const void* b2  = d_in[10];

    // workspace carve-up (256B aligned) — ~32.5 MB (proven footprint + 50KB)
    char* ws = (char*)d_ws;
    size_t p = 0;
    auto alloc = [&](size_t bytes) -> char* {
        p = (p + 255) & ~(size_t)255;
        char* r = ws + p;
        p += bytes;
        return r;
    };
    int* flag        = (int*)alloc(4);
    float* biasbuf   = (float*)alloc(48 * 4);
    uint32_t* wpk1   = (uint32_t*)alloc(256 * 4);
    uint32_t* wpk2   = (uint32_t*)alloc(512 * 4);
    int* bucketCnt   = (int*)alloc(NB * 4);
    int* base        = (int*)alloc((NB + 1) * 4);
    int* gcur        = (int*)alloc((size_t)NB * GSTR * 4);       // 50 KB (line-padded)
    int* off         = (int*)alloc(((size_t)2 * Nn + 1) * 4);    // 400 KB
    uint32_t* recf   = (uint32_t*)alloc((size_t)2 * Ee * 4);     // 6.4 MB
    uint32_t* h1rows = (uint32_t*)alloc((size_t)Nn * ROWD * 4);  // 12.8 MB
    uint64_t* gout   = (uint64_t*)alloc((size_t)2 * Ee * 8);     // 12.8 MB
    // xrows lives in d_out (fully overwritten by k_layer2; proven placement)
    uint32_t* xrows  = (uint32_t*)d_out;

    hipMemsetAsync(bucketCnt, 0, NB * sizeof(int), stream);
    hipLaunchKernelGGL(k_count_detect, dim3(257), dim3(256), 0, stream,
                       ei0, ei1, bucketCnt,
                       (const unsigned short*)X, 16384, flag, W1, b1, W2, b2,
                       biasbuf, wpk1, wpk2);
    hipLaunchKernelGGL(k_bucketscan, dim3(1), dim3(512), 0, stream,
                       bucketCnt, base, gcur);
    hipLaunchKernelGGL(k_bin_tr, dim3(BINB + TRB), dim3(256), 0, stream,
                       flag, ei0, w0, ei1, w1, gcur, gout, X, xrows);
    hipLaunchKernelGGL(k_csr, dim3(NB), dim3(256), 0, stream,
                       base, gout, off, recf);
    hipLaunchKernelGGL(k_layer1, dim3(Nn / 4), dim3(256), 0, stream,
                       xrows, off, recf, rn0, wpk1, biasbuf, h1rows);
    hipLaunchKernelGGL(k_layer2, dim3(Nn / 4), dim3(256), 0, stream,
                       flag, h1rows, off, recf, rn1, wpk2, biasbuf, d_out);
    (void)in_sizes; (void)n_in; (void)out_size; (void)ws_size;
}